// Round 9
// baseline (35.011 us; speedup 1.0000x reference)
//
#include <hip/hip_runtime.h>

// FutureEncoder: out[b,t,:] = sum_j softmax_j(dot(x[b,t], x[b,t+1+j])) * x[b,t+1+j],
// j in [0,16), valid iff t+1+j < S. fp32 throughout.
//
// Round 9: maximize TLP, drop all sharing machinery. R7/R8 proved LDS staging
// loses more to barriers/occupancy than it wins in traffic (caches absorb the
// window reuse). R6's cap was the grid: 4096 waves = 4 waves/SIMD. Now ONE t
// per wave -> 8192 waves = 8/SIMD, with per-wave state (query 16 + acc 16 +
// m,s) small enough for the 64-VGPR budget 8 waves/SIMD needs
// (__launch_bounds__(256,8)). Dot work doubles vs TPW=2 (~6.6us/SIMD issue,
// still under the ~10.6us HBM floor); redundant row reads hit L1/L2. Full
// 16-row compile-time unroll; XCD strip swizzle for L2 locality.

namespace {
constexpr int kB   = 2;
constexpr int kS   = 4096;
constexpr int kH   = 1024;
constexpr int kK   = 16;
constexpr int kFR  = kH / (64 * 4);     // 4 float4 fragments per lane per row
constexpr int kWavesPerBlk = 4;         // 256 threads
constexpr int kBlocks = kB * kS / kWavesPerBlk;  // 2048 blocks, 8/CU
constexpr int kXCD = 8;
}

__global__ __launch_bounds__(256, 8)
void future_encoder_kernel(const float* __restrict__ x, float* __restrict__ out) {
  const int lane = (int)(threadIdx.x & 63);
  const int wib  = (int)(threadIdx.x >> 6);

  // XCD strip swizzle: blocks round-robin over 8 XCDs; remap so each XCD gets
  // a contiguous strip of 256 virtual blocks (1024 consecutive t's).
  const int vb   = (int)(blockIdx.x % kXCD) * (kBlocks / kXCD) + (int)(blockIdx.x / kXCD);
  const int tg   = vb * kWavesPerBlk + wib;     // global t index, 0..8191
  const int b    = tg / kS;
  const int t    = tg % kS;
  const float* __restrict__ xb = x   + (size_t)b * kS * kH;
  float* __restrict__       ob = out + (size_t)b * kS * kH;
  const int col = lane * 4;

  // Query fragments: lane holds elements {p*256 + lane*4 .. +3}
  float4 xt[kFR];
#pragma unroll
  for (int p = 0; p < kFR; ++p)
    xt[p] = *(const float4*)(xb + (size_t)t * kH + p * 256 + col);

  // Online-softmax state
  float m = -1e30f, s = 0.f;
  float4 acc[kFR];
#pragma unroll
  for (int p = 0; p < kFR; ++p) acc[p] = make_float4(0.f, 0.f, 0.f, 0.f);

  // Fully-unrolled window loop: j = 0..15, row t+1+j (clamped; masked below).
#pragma unroll
  for (int j = 0; j < kK; ++j) {
    const int rr = t + 1 + j;
    const int r  = (rr < kS) ? rr : (kS - 1);

    float4 w[kFR];
#pragma unroll
    for (int p = 0; p < kFR; ++p)
      w[p] = *(const float4*)(xb + (size_t)r * kH + p * 256 + col);

    float a0 = 0.f, a1 = 0.f;
#pragma unroll
    for (int p = 0; p < kFR; ++p) {
      a0 = fmaf(xt[p].x, w[p].x, a0);
      a1 = fmaf(xt[p].y, w[p].y, a1);
      a0 = fmaf(xt[p].z, w[p].z, a0);
      a1 = fmaf(xt[p].w, w[p].w, a1);
    }
    float sc = a0 + a1;

    // 64-lane butterfly reduce -> wave-uniform score
#pragma unroll
    for (int off = 32; off >= 1; off >>= 1)
      sc += __shfl_xor(sc, off, 64);

    // Online update, masked by the wave-uniform tail test
    if (rr < kS) {
      if (sc <= m) {
        const float p2 = __expf(sc - m);
        s += p2;
#pragma unroll
        for (int p = 0; p < kFR; ++p) {
          acc[p].x = fmaf(p2, w[p].x, acc[p].x);
          acc[p].y = fmaf(p2, w[p].y, acc[p].y);
          acc[p].z = fmaf(p2, w[p].z, acc[p].z);
          acc[p].w = fmaf(p2, w[p].w, acc[p].w);
        }
      } else {
        const float r2 = __expf(m - sc);   // 0 on first valid row (m = -1e30)
        m = sc;
        s = fmaf(s, r2, 1.f);
#pragma unroll
        for (int p = 0; p < kFR; ++p) {
          acc[p].x = fmaf(acc[p].x, r2, w[p].x);
          acc[p].y = fmaf(acc[p].y, r2, w[p].y);
          acc[p].z = fmaf(acc[p].z, r2, w[p].z);
          acc[p].w = fmaf(acc[p].w, r2, w[p].w);
        }
      }
    }
  }

  // Epilogue: out = acc / s  (s==0 only for t==S-1 -> exact zeros)
  const float inv = (s > 0.f) ? (1.f / s) : 0.f;
#pragma unroll
  for (int p = 0; p < kFR; ++p) {
    float4 o;
    o.x = acc[p].x * inv;
    o.y = acc[p].y * inv;
    o.z = acc[p].z * inv;
    o.w = acc[p].w * inv;
    *(float4*)(ob + (size_t)t * kH + p * 256 + col) = o;
  }
}

extern "C" void kernel_launch(void* const* d_in, const int* in_sizes, int n_in,
                              void* d_out, int out_size, void* d_ws, size_t ws_size,
                              hipStream_t stream) {
  const float* x = (const float*)d_in[0];
  float* out = (float*)d_out;
  hipLaunchKernelGGL(future_encoder_kernel, dim3(kBlocks), dim3(256), 0, stream,
                     x, out);
}